// Round 7
// baseline (63.928 us; speedup 1.0000x reference)
//
#include <hip/hip_runtime.h>

// Problem constants (from reference)
#define NQ 6
#define DD 64            // 2^NQ
#define NF 4
#define GG 14
#define GG2 196
#define GG3 2744
#define NSIDE 12
#define PP 1728          // NSIDE^3
#define NC 40
#define BB 16
#define LAM 0.1f
#define FEAT_LEN (NF*PP*NQ)   // 41472
#define KCH 512
#define NCHUNK 81             // 41472 / 512
#define CTILES 5              // 40 / 8

// ---------- helpers ----------

// First column (u00,u10) of PennyLane Rot(phi,th,om)
__device__ __forceinline__ void rotcol(float phi, float th, float om,
    float& c0r, float& c0i, float& c1r, float& c1i)
{
    float s, c, sap, cap, sam, cam;
    __sincosf(0.5f*th, &s, &c);
    __sincosf(0.5f*(phi+om), &sap, &cap);
    __sincosf(0.5f*(phi-om), &sam, &cam);
    c0r = cap*c; c0i = -sap*c;
    c1r = cam*s; c1i = -sam*s;
}

// Sparse spread over 16 local amps: support multiples of 2*MASK, first col only.
template<int MASK>
__device__ __forceinline__ void spreadL16(float* sr, float* si,
    float c0r, float c0i, float c1r, float c1i)
{
    #pragma unroll
    for (int i = 0; i < 8/MASK; ++i) {
        const int d0 = i*2*MASK, d1 = d0 + MASK;
        float a0r = sr[d0], a0i = si[d0];
        sr[d1] = c1r*a0r - c1i*a0i;
        si[d1] = c1r*a0i + c1i*a0r;
        sr[d0] = c0r*a0r - c0i*a0i;
        si[d0] = c0r*a0i + c0i*a0r;
    }
}

// Full 1q gate on local bit TMASK over 16 amps (coefficients may encode identity)
template<int TMASK>
__device__ __forceinline__ void gate1L16(float* sr, float* si, float4 A, float4 Bq)
{
    #pragma unroll
    for (int d0 = 0; d0 < 16; ++d0) {
        if (d0 & TMASK) continue;
        const int d1 = d0 | TMASK;
        float a0r = sr[d0], a0i = si[d0];
        float a1r = sr[d1], a1i = si[d1];
        sr[d0] = A.x*a0r - A.y*a0i + A.z*a1r - A.w*a1i;
        si[d0] = A.x*a0i + A.y*a0r + A.z*a1i + A.w*a1r;
        sr[d1] = Bq.x*a0r - Bq.y*a0i + Bq.z*a1r - Bq.w*a1i;
        si[d1] = Bq.x*a0i + Bq.y*a0r + Bq.z*a1i + Bq.w*a1r;
    }
}

// Local controlled Rot (control & target both local bits)
template<int CMASK, int TMASK>
__device__ __forceinline__ void crotL16(float* sr, float* si, float4 A, float4 Bq)
{
    #pragma unroll
    for (int d0 = 0; d0 < 16; ++d0) {
        if (!(d0 & CMASK) || (d0 & TMASK)) continue;
        const int d1 = d0 | TMASK;
        float a0r = sr[d0], a0i = si[d0];
        float a1r = sr[d1], a1i = si[d1];
        sr[d0] = A.x*a0r - A.y*a0i + A.z*a1r - A.w*a1i;
        si[d0] = A.x*a0i + A.y*a0r + A.z*a1i + A.w*a1r;
        sr[d1] = Bq.x*a0r - Bq.y*a0i + Bq.z*a1r - Bq.w*a1i;
        si[d1] = Bq.x*a0i + Bq.y*a0r + Bq.z*a1i + Bq.w*a1r;
    }
}

// ---------- sim: 4 threads per circuit; block = 1 patch (256 thr) ----------
// Thread layout: t = b*16 + f*4 + h2 ; h2 bit0 = state bit4 (qubit1),
// h2 bit1 = state bit5 (qubit0). Local amps = state bits [3:0].

__global__ __launch_bounds__(256) void sim_kernel(
    const float* __restrict__ x,      // [B,14,14,14]
    const float* __restrict__ theta,  // [NF,1,6,3]
    float* __restrict__ feats,        // [B][NF][PP][NQ]
    float* __restrict__ ip2)          // [PP][4]
{
    const int p = blockIdx.x;
    const int t = threadIdx.x;        // 256 threads = 4 waves
    const int w = t >> 6;
    const int lane = t & 63;
    const int b = t >> 4;             // 0..15
    const int f = (t >> 2) & 3;
    const bool g4 = (t & 1) != 0;     // state bit4 (qubit1)
    const bool g5 = (t & 2) != 0;     // state bit5 (qubit0)

    __shared__ __align__(16) float scrot[NF*NQ][8];
    __shared__ __align__(16) float scomp[BB][NQ][4];   // composed enc columns

    if (t < NF*NQ) {
        const float* a = theta + t*3;
        float s, c, sap, cap, sam, cam;
        __sincosf(0.5f*a[1], &s, &c);
        __sincosf(0.5f*(a[0]+a[2]), &sap, &cap);
        __sincosf(0.5f*(a[0]-a[2]), &sam, &cam);
        scrot[t][0] =  cap*c; scrot[t][1] = -sap*c;
        scrot[t][2] = -cam*s; scrot[t][3] = -sam*s;
        scrot[t][4] =  cam*s; scrot[t][5] = -sam*s;
        scrot[t][6] =  cap*c; scrot[t][7] =  sap*c;
    }

    const int px = p/(NSIDE*NSIDE), py = (p/NSIDE)%NSIDE, pz = p%NSIDE;

    // Setup: threads [64,160) build composed encoding column (b2, q).
    // Qubit q: gate q (then gate q+6 if q<3) — gates on distinct qubits commute.
    if (t >= 64 && t < 64 + BB*NQ) {
        const int idx = t - 64;
        const int b2 = idx / NQ, q = idx % NQ;
        const float* xp = x + (size_t)b2*GG3 + px*GG2 + py*GG + pz;
        #define SPV(i) xp[((i)/9)*GG2 + (((i)/3)%3)*GG + ((i)%3)]
        float c0r, c0i, c1r, c1i;
        rotcol(SPV(3*q), SPV(3*q+1), SPV(3*q+2), c0r, c0i, c1r, c1i);
        if (q < 3) {
            const int k2 = 3*(q+6);
            float s_,c_,sap_,cap_,sam_,cam_;
            __sincosf(0.5f*SPV(k2+1), &s_, &c_);
            __sincosf(0.5f*(SPV(k2)+SPV(k2+2)), &sap_, &cap_);
            __sincosf(0.5f*(SPV(k2)-SPV(k2+2)), &sam_, &cam_);
            float b00r=cap_*c_, b00i=-sap_*c_, b01r=-cam_*s_, b01i=-sam_*s_;
            float b10r=cam_*s_, b10i=-sam_*s_, b11r=cap_*c_,  b11i= sap_*c_;
            float n0r = b00r*c0r - b00i*c0i + b01r*c1r - b01i*c1i;
            float n0i = b00r*c0i + b00i*c0r + b01r*c1i + b01i*c1r;
            float n1r = b10r*c0r - b10i*c0i + b11r*c1r - b11i*c1i;
            float n1i = b10r*c0i + b10i*c0r + b11r*c1i + b11i*c1r;
            c0r=n0r; c0i=n0i; c1r=n1r; c1i=n1i;
        }
        #undef SPV
        scomp[b2][q][0]=c0r; scomp[b2][q][1]=c0i;
        scomp[b2][q][2]=c1r; scomp[b2][q][3]=c1i;
    }
    __syncthreads();

    float sr[16], si[16];

    // ---- encoding from composed columns (input |0>):
    // qubit0 (bit5=g5), qubit1 (bit4=g4): select column entries, complex mul.
    {
        float4 C0 = *(const float4*)&scomp[b][0][0];
        float4 C1 = *(const float4*)&scomp[b][1][0];
        float e0r = g5 ? C0.z : C0.x, e0i = g5 ? C0.w : C0.y;
        float e1r = g4 ? C1.z : C1.x, e1i = g4 ? C1.w : C1.y;
        sr[0] = e0r*e1r - e0i*e1i;
        si[0] = e0r*e1i + e0i*e1r;
    }
    // qubits 2..5 -> local bits 3..0: sparse spreads
    #define ENC(Q, MASK) { \
        float4 C = *(const float4*)&scomp[b][Q][0]; \
        spreadL16<MASK>(sr, si, C.x, C.y, C.z, C.w); }
    ENC(2, 8) ENC(3, 4) ENC(4, 2) ENC(5, 1)
    #undef ENC

    // ---- CRot ring for feature f: control qubit i -> target qubit (i+1)%6
    // CR0: ctrl q0 (bit5=g5), tgt q1 (bit4=g4) -> exchange lane^1,
    // coefficients selected per lane (identity when ctrl=0).
    {
        float4 A  = *(const float4*)&scrot[f*NQ + 0][0];
        float4 Bq = *(const float4*)&scrot[f*NQ + 0][4];
        float cAr = g4 ? Bq.z : A.x, cAi = g4 ? Bq.w : A.y;
        float cBr = g4 ? Bq.x : A.z, cBi = g4 ? Bq.y : A.w;
        if (!g5) { cAr = 1.f; cAi = 0.f; cBr = 0.f; cBi = 0.f; }
        #pragma unroll
        for (int d = 0; d < 16; ++d) {
            float pr_ = __shfl_xor(sr[d], 1);
            float pi_ = __shfl_xor(si[d], 1);
            float nr = cAr*sr[d] - cAi*si[d] + cBr*pr_ - cBi*pi_;
            float ni = cAr*si[d] + cAi*sr[d] + cBr*pi_ + cBi*pr_;
            sr[d] = nr; si[d] = ni;
        }
    }
    // CR1: ctrl q1 (bit4=g4), tgt q2 (local bit3): identity-coef when ctrl=0
    {
        float4 A  = *(const float4*)&scrot[f*NQ + 1][0];
        float4 Bq = *(const float4*)&scrot[f*NQ + 1][4];
        if (!g4) { A = make_float4(1.f,0.f,0.f,0.f); Bq = make_float4(0.f,0.f,1.f,0.f); }
        gate1L16<8>(sr, si, A, Bq);
    }
    // CR2..CR4: fully local
    #define CRL(I, CM, TM) { \
        float4 A  = *(const float4*)&scrot[f*NQ + (I)][0]; \
        float4 Bq = *(const float4*)&scrot[f*NQ + (I)][4]; \
        crotL16<CM, TM>(sr, si, A, Bq); }
    CRL(2, 8, 4) CRL(3, 4, 2) CRL(4, 2, 1)
    #undef CRL
    // CR5: ctrl q5 (local bit0), tgt q0 (bit5=g5) -> exchange lane^2 on odd amps
    {
        float4 A  = *(const float4*)&scrot[f*NQ + 5][0];
        float4 Bq = *(const float4*)&scrot[f*NQ + 5][4];
        float cAr = g5 ? Bq.z : A.x, cAi = g5 ? Bq.w : A.y;
        float cBr = g5 ? Bq.x : A.z, cBi = g5 ? Bq.y : A.w;
        #pragma unroll
        for (int d = 1; d < 16; d += 2) {
            float pr_ = __shfl_xor(sr[d], 2);
            float pi_ = __shfl_xor(si[d], 2);
            float nr = cAr*sr[d] - cAi*si[d] + cBr*pr_ - cBi*pi_;
            float ni = cAr*si[d] + cAi*sr[d] + cBr*pi_ + cBi*pr_;
            sr[d] = nr; si[d] = ni;
        }
    }

    // ---- probabilities overwrite sr (si dead)
    #pragma unroll
    for (int d = 0; d < 16; ++d) sr[d] = sr[d]*sr[d] + si[d]*si[d];

    // ---- loss pair-dots: f-partners at lane^4,^8,^12 (same b,h2)
    float lsum = 0.f;
    #pragma unroll
    for (int xm = 4; xm <= 12; xm += 4) {
        float partial = 0.f;
        #pragma unroll
        for (int d = 0; d < 16; ++d)
            partial += sr[d] * __shfl_xor(sr[d], xm);
        // combine over the 4 h2 lanes (butterfly keeps value in all lanes)
        partial += __shfl_xor(partial, 1);
        partial += __shfl_xor(partial, 2);
        lsum += partial*partial;
    }
    #pragma unroll
    for (int m = 1; m < 64; m <<= 1) lsum += __shfl_xor(lsum, m);
    if (lane == 0) ip2[p*4 + w] = lsum;   // 4x-counted; finalize scales by 1/4

    // ---- expvals: local signed tree (qubits 5..2), then bit4/bit5 signs,
    // then combine over the 4 h2 lanes.
    float ev5 = 0.f, ev4 = 0.f, ev3 = 0.f, ev2 = 0.f;
    #pragma unroll
    for (int i = 0; i < 8; ++i) { ev5 += sr[2*i] - sr[2*i+1]; sr[i] = sr[2*i] + sr[2*i+1]; }
    #pragma unroll
    for (int i = 0; i < 4; ++i) { ev4 += sr[2*i] - sr[2*i+1]; sr[i] = sr[2*i] + sr[2*i+1]; }
    #pragma unroll
    for (int i = 0; i < 2; ++i) { ev3 += sr[2*i] - sr[2*i+1]; sr[i] = sr[2*i] + sr[2*i+1]; }
    ev2 = sr[0] - sr[1];
    float tot = sr[0] + sr[1];
    float ev1 = g4 ? -tot : tot;
    float ev0 = g5 ? -tot : tot;
    #define COMB(e) { e += __shfl_xor(e, 1); e += __shfl_xor(e, 2); }
    COMB(ev0) COMB(ev1) COMB(ev2) COMB(ev3) COMB(ev4) COMB(ev5)
    #undef COMB

    float* fo = feats + (((size_t)b*NF + f)*PP + p)*NQ;
    const int h2 = t & 3;
    if (h2 == 0) { fo[0] = ev0; fo[1] = ev1; fo[2] = ev2; }
    else if (h2 == 1) { fo[3] = ev3; fo[4] = ev4; fo[5] = ev5; }
}

// ---------- logits phase A: K-split, W read once ----------

__global__ __launch_bounds__(128) void logitsA(
    const float* __restrict__ feats,   // [BB][FEAT_LEN]
    const float* __restrict__ W,       // [NC][FEAT_LEN]
    float* __restrict__ partial)       // [NC][BB][NCHUNK]
{
    const int chunk = blockIdx.x;      // 0..80
    const int ctile = blockIdx.y;      // 0..4
    const int t = threadIdx.x;         // 128
    const int jbase = chunk * KCH;

    __shared__ __align__(16) float fs[BB][KCH + 4];

    #pragma unroll
    for (int i = 0; i < 16; ++i) {
        const int gi = i*128 + t;
        const int br = gi >> 7;
        const int c4 = gi & 127;
        float4 v = *(const float4*)(feats + (size_t)br*FEAT_LEN + jbase + c4*4);
        *(float4*)&fs[br][c4*4] = v;
    }
    __syncthreads();

    const int cl = t >> 4, b = t & 15;
    const int c = ctile*8 + cl;
    const float* wr = W + (size_t)c*FEAT_LEN + jbase;
    float acc = 0.f;
    #pragma unroll 8
    for (int j4 = 0; j4 < KCH/4; ++j4) {
        float4 wv = *(const float4*)(wr + j4*4);
        float4 fv = *(const float4*)&fs[b][j4*4];
        acc += wv.x*fv.x + wv.y*fv.y + wv.z*fv.z + wv.w*fv.w;
    }
    partial[((size_t)c*BB + b)*NCHUNK + chunk] = acc;
}

// ---------- phase B: logits reduce + bias, and loss reduce ----------

__global__ __launch_bounds__(768) void finalize_kernel(
    const float* __restrict__ partial, const float* __restrict__ bias,
    const float* __restrict__ ip2, float* __restrict__ out)
{
    const int t = threadIdx.x;
    if (t < BB*NC) {
        const int b = t / NC, c = t % NC;
        const float* pp = partial + ((size_t)c*BB + b)*NCHUNK;
        float acc = bias[c];
        #pragma unroll 27
        for (int i = 0; i < NCHUNK; ++i) acc += pp[i];
        out[t] = acc;
    } else if (t >= 704) {
        const int lane = t - 704;
        float acc = 0.f;
        for (int i = lane; i < PP*4; i += 64) acc += ip2[i];
        #pragma unroll
        for (int m = 1; m < 64; m <<= 1) acc += __shfl_xor(acc, m);
        if (lane == 0)   // extra 1/4: dots are 4x-counted across h2 lanes
            out[BB*NC] = acc * (LAM / (float)(NF*(NF-1)) / (float)BB * 0.25f);
    }
}

extern "C" void kernel_launch(void* const* d_in, const int* in_sizes, int n_in,
                              void* d_out, int out_size, void* d_ws, size_t ws_size,
                              hipStream_t stream) {
    const float* x     = (const float*)d_in[0];  // [16,14,14,14]
    const float* theta = (const float*)d_in[1];  // [4,1,6,3]
    const float* W     = (const float*)d_in[2];  // [40,41472]
    const float* bias  = (const float*)d_in[3];  // [40]
    float* out = (float*)d_out;                  // [640 logits][1 loss]

    float* feats   = (float*)d_ws;                       // BB*FEAT_LEN
    float* ip2     = feats + (size_t)BB * FEAT_LEN;      // PP*4
    float* partial = ip2 + (size_t)PP * 4;               // NC*BB*NCHUNK

    sim_kernel<<<PP, 256, 0, stream>>>(x, theta, feats, ip2);
    logitsA<<<dim3(NCHUNK, CTILES), 128, 0, stream>>>(feats, W, partial);
    finalize_kernel<<<1, 768, 0, stream>>>(partial, bias, ip2, out);
}

// Round 8
// 45.953 us; speedup vs baseline: 1.3912x; 1.3912x over previous
//
#include <hip/hip_runtime.h>

// Problem constants (from reference)
#define NQ 6
#define DD 64            // 2^NQ
#define NF 4
#define GG 14
#define GG2 196
#define GG3 2744
#define NSIDE 12
#define PP 1728          // NSIDE^3
#define NC 40
#define BB 16
#define LAM 0.1f
#define FEAT_LEN (NF*PP*NQ)   // 41472
#define KCH 512
#define NCHUNK 81             // 41472 / 512
#define CTILES 5              // 40 / 8
#define PBLK 4                // patches per block

// ---------- helpers ----------

template<int CTRL>
__device__ __forceinline__ float fdpp(float v) {
    return __int_as_float(__builtin_amdgcn_mov_dpp(__float_as_int(v), CTRL, 0xF, 0xF, true));
}
// quad_perm ctrl: xor1=0xB1, xor2=0x4E, xor3=0x1B

// First column (u00,u10) of PennyLane Rot(phi,th,om)
__device__ __forceinline__ void rotcol(float phi, float th, float om,
    float& c0r, float& c0i, float& c1r, float& c1i)
{
    float s, c, sap, cap, sam, cam;
    __sincosf(0.5f*th, &s, &c);
    __sincosf(0.5f*(phi+om), &sap, &cap);
    __sincosf(0.5f*(phi-om), &sam, &cam);
    c0r = cap*c; c0i = -sap*c;
    c1r = cam*s; c1i = -sam*s;
}

// Sparse spread: support = multiples of 2*MASK, only first gate column needed.
template<int MASK>
__device__ __forceinline__ void spread(float* ar, float* ai,
    float c0r, float c0i, float c1r, float c1i)
{
    #pragma unroll
    for (int i = 0; i < 32/MASK; ++i) {
        const int d0 = i*2*MASK, d1 = d0 + MASK;
        float a0r = ar[d0], a0i = ai[d0];
        ar[d1] = c1r*a0r - c1i*a0i;
        ai[d1] = c1r*a0i + c1i*a0r;
        ar[d0] = c0r*a0r - c0i*a0i;
        ai[d0] = c0r*a0i + c0i*a0r;
    }
}

// Controlled Rot: apply U on target bit TMASK only where control bit CMASK=1.
template<int CMASK, int TMASK>
__device__ __forceinline__ void crot(float* ar, float* ai, float4 A, float4 Bq)
{
    #pragma unroll
    for (int d0 = 0; d0 < DD; ++d0) {
        if (!(d0 & CMASK) || (d0 & TMASK)) continue;
        const int d1 = d0 | TMASK;
        float a0r = ar[d0], a0i = ai[d0];
        float a1r = ar[d1], a1i = ai[d1];
        ar[d0] = A.x*a0r - A.y*a0i + A.z*a1r - A.w*a1i;
        ai[d0] = A.x*a0i + A.y*a0r + A.z*a1i + A.w*a1r;
        ar[d1] = Bq.x*a0r - Bq.y*a0i + Bq.z*a1r - Bq.w*a1i;
        ai[d1] = Bq.x*a0i + Bq.y*a0r + Bq.z*a1i + Bq.w*a1r;
    }
}

// ---------- sim: 1 thread = 1 circuit (p,b,f); block = 4 p's ----------
// NOTE: no min-waves hint (R5 lesson: (N,k) caps VGPR and causes spill).

__global__ __launch_bounds__(256) void sim_kernel(
    const float* __restrict__ x,      // [B,14,14,14]
    const float* __restrict__ theta,  // [NF,1,6,3]
    float* __restrict__ feats,        // [B][NF][PP][NQ]
    float* __restrict__ ip2)          // [PP]
{
    const int t = threadIdx.x;
    const int w = t >> 6;                       // wave -> which p
    const int p = blockIdx.x * PBLK + w;
    const int lane = t & 63;
    const int b = lane >> 2, f = lane & 3;

    __shared__ __align__(16) float scrot[NF*NQ][8];
    __shared__ __align__(16) float scomp[PBLK][BB][NQ][4];  // composed enc columns

    if (t < NF*NQ) {
        const float* a = theta + t*3;
        float s, c, sap, cap, sam, cam;
        __sincosf(0.5f*a[1], &s, &c);
        __sincosf(0.5f*(a[0]+a[2]), &sap, &cap);
        __sincosf(0.5f*(a[0]-a[2]), &sam, &cam);
        scrot[t][0] =  cap*c; scrot[t][1] = -sap*c;
        scrot[t][2] = -cam*s; scrot[t][3] = -sam*s;
        scrot[t][4] =  cam*s; scrot[t][5] = -sam*s;
        scrot[t][6] =  cap*c; scrot[t][7] =  sap*c;
    }

    // Setup: 384 composed encoding columns (pw, b2, q); threads t and t+256.
    // Qubit q: gate q (then gate q+6 if q<3) — gates on distinct qubits commute.
    #pragma unroll
    for (int c = t; c < PBLK*BB*NQ; c += 256) {
        const int pw = c / (BB*NQ);
        const int rem = c % (BB*NQ);
        const int b2 = rem / NQ, q = rem % NQ;
        const int pc = blockIdx.x * PBLK + pw;
        const int px = pc/(NSIDE*NSIDE), py = (pc/NSIDE)%NSIDE, pz = pc%NSIDE;
        const float* xp = x + (size_t)b2*GG3 + px*GG2 + py*GG + pz;
        #define SPV(i) xp[((i)/9)*GG2 + (((i)/3)%3)*GG + ((i)%3)]
        float c0r, c0i, c1r, c1i;
        rotcol(SPV(3*q), SPV(3*q+1), SPV(3*q+2), c0r, c0i, c1r, c1i);
        if (q < 3) {
            const int k2 = 3*(q+6);
            float s_,c_,sap_,cap_,sam_,cam_;
            __sincosf(0.5f*SPV(k2+1), &s_, &c_);
            __sincosf(0.5f*(SPV(k2)+SPV(k2+2)), &sap_, &cap_);
            __sincosf(0.5f*(SPV(k2)-SPV(k2+2)), &sam_, &cam_);
            float b00r=cap_*c_, b00i=-sap_*c_, b01r=-cam_*s_, b01i=-sam_*s_;
            float b10r=cam_*s_, b10i=-sam_*s_, b11r=cap_*c_,  b11i= sap_*c_;
            float n0r = b00r*c0r - b00i*c0i + b01r*c1r - b01i*c1i;
            float n0i = b00r*c0i + b00i*c0r + b01r*c1i + b01i*c1r;
            float n1r = b10r*c0r - b10i*c0i + b11r*c1r - b11i*c1i;
            float n1i = b10r*c0i + b10i*c0r + b11r*c1i + b11i*c1r;
            c0r=n0r; c0i=n0i; c1r=n1r; c1i=n1i;
        }
        #undef SPV
        scomp[pw][b2][q][0]=c0r; scomp[pw][b2][q][1]=c0i;
        scomp[pw][b2][q][2]=c1r; scomp[pw][b2][q][3]=c1i;
    }
    __syncthreads();

    float ar[DD], ai[DD];

    // ---- encoding from composed columns (input |0>), qubit q -> bit 5-q
    {
        float4 C = *(const float4*)&scomp[w][b][0][0];
        ar[0] = C.x; ai[0] = C.y; ar[32] = C.z; ai[32] = C.w;
    }
    #define ENC(Q, MASK) { \
        float4 C = *(const float4*)&scomp[w][b][Q][0]; \
        spread<MASK>(ar, ai, C.x, C.y, C.z, C.w); }
    ENC(1, 16) ENC(2, 8) ENC(3, 4) ENC(4, 2) ENC(5, 1)
    #undef ENC

    // ---- CRot ring for feature f: control qubit i -> target qubit (i+1)%6
    #define CR(I, CM, TM) { \
        float4 A  = *(const float4*)&scrot[f*NQ + (I)][0]; \
        float4 Bq = *(const float4*)&scrot[f*NQ + (I)][4]; \
        crot<CM, TM>(ar, ai, A, Bq); }
    CR(0, 32, 16) CR(1, 16, 8) CR(2, 8, 4) CR(3, 4, 2) CR(4, 2, 1) CR(5, 1, 32)
    #undef CR

    // ---- probabilities overwrite ar (ai dead after this)
    #pragma unroll
    for (int d = 0; d < DD; ++d) ar[d] = ar[d]*ar[d] + ai[d]*ai[d];

    // ---- loss pair-dots via DPP quad_perm (quad = same (p,b), f=0..3)
    float dot1 = 0.f, dot2 = 0.f, dot3 = 0.f;
    #pragma unroll
    for (int d = 0; d < DD; ++d) {
        dot1 += ar[d] * fdpp<0xB1>(ar[d]);
        dot2 += ar[d] * fdpp<0x4E>(ar[d]);
        dot3 += ar[d] * fdpp<0x1B>(ar[d]);
    }
    float lc = dot1*dot1 + dot2*dot2 + dot3*dot3;
    #pragma unroll
    for (int m = 1; m < 64; m <<= 1) lc += __shfl_xor(lc, m);
    if (lane == 0) ip2[p] = lc;

    // ---- expvals: signed in-place reduction tree over probs (in ar)
    float ev[NQ];
    #pragma unroll
    for (int lvl = 0; lvl < NQ; ++lvl) {
        const int n = DD >> (lvl + 1);
        float diff = 0.f;
        #pragma unroll
        for (int i = 0; i < n; ++i) diff += ar[2*i] - ar[2*i+1];
        ev[5 - lvl] = diff;
        #pragma unroll
        for (int i = 0; i < n; ++i) ar[i] = ar[2*i] + ar[2*i+1];
    }

    float* fo = feats + (((size_t)b*NF + f)*PP + p)*NQ;
    #pragma unroll
    for (int q = 0; q < NQ; ++q) fo[q] = ev[q];
}

// ---------- logits phase A: K-split, W read once ----------

__global__ __launch_bounds__(128) void logitsA(
    const float* __restrict__ feats,   // [BB][FEAT_LEN]
    const float* __restrict__ W,       // [NC][FEAT_LEN]
    float* __restrict__ partial)       // [NC][BB][NCHUNK]
{
    const int chunk = blockIdx.x;      // 0..80
    const int ctile = blockIdx.y;      // 0..4
    const int t = threadIdx.x;         // 128
    const int jbase = chunk * KCH;

    __shared__ __align__(16) float fs[BB][KCH + 4];

    #pragma unroll
    for (int i = 0; i < 16; ++i) {
        const int gi = i*128 + t;
        const int br = gi >> 7;
        const int c4 = gi & 127;
        float4 v = *(const float4*)(feats + (size_t)br*FEAT_LEN + jbase + c4*4);
        *(float4*)&fs[br][c4*4] = v;
    }
    __syncthreads();

    const int cl = t >> 4, b = t & 15;
    const int c = ctile*8 + cl;
    const float* wr = W + (size_t)c*FEAT_LEN + jbase;
    float acc = 0.f;
    #pragma unroll 8
    for (int j4 = 0; j4 < KCH/4; ++j4) {
        float4 wv = *(const float4*)(wr + j4*4);
        float4 fv = *(const float4*)&fs[b][j4*4];
        acc += wv.x*fv.x + wv.y*fv.y + wv.z*fv.z + wv.w*fv.w;
    }
    partial[((size_t)c*BB + b)*NCHUNK + chunk] = acc;
}

// ---------- phase B: logits reduce + bias, and loss reduce ----------

__global__ __launch_bounds__(768) void finalize_kernel(
    const float* __restrict__ partial, const float* __restrict__ bias,
    const float* __restrict__ ip2, float* __restrict__ out)
{
    const int t = threadIdx.x;
    if (t < BB*NC) {
        const int b = t / NC, c = t % NC;
        const float* pp = partial + ((size_t)c*BB + b)*NCHUNK;
        float acc = bias[c];
        #pragma unroll 27
        for (int i = 0; i < NCHUNK; ++i) acc += pp[i];
        out[t] = acc;
    } else if (t >= 704) {
        const int lane = t - 704;
        float acc = 0.f;
        for (int i = lane; i < PP; i += 64) acc += ip2[i];
        #pragma unroll
        for (int m = 1; m < 64; m <<= 1) acc += __shfl_xor(acc, m);
        if (lane == 0)
            out[BB*NC] = acc * (LAM / (float)(NF*(NF-1)) / (float)BB);
    }
}

extern "C" void kernel_launch(void* const* d_in, const int* in_sizes, int n_in,
                              void* d_out, int out_size, void* d_ws, size_t ws_size,
                              hipStream_t stream) {
    const float* x     = (const float*)d_in[0];  // [16,14,14,14]
    const float* theta = (const float*)d_in[1];  // [4,1,6,3]
    const float* W     = (const float*)d_in[2];  // [40,41472]
    const float* bias  = (const float*)d_in[3];  // [40]
    float* out = (float*)d_out;                  // [640 logits][1 loss]

    float* feats   = (float*)d_ws;                       // BB*FEAT_LEN
    float* ip2     = feats + (size_t)BB * FEAT_LEN;      // PP
    float* partial = ip2 + PP;                           // NC*BB*NCHUNK

    sim_kernel<<<PP/PBLK, 256, 0, stream>>>(x, theta, feats, ip2);
    logitsA<<<dim3(NCHUNK, CTILES), 128, 0, stream>>>(feats, W, partial);
    finalize_kernel<<<1, 768, 0, stream>>>(partial, bias, ip2, out);
}